// Round 7
// baseline (60.663 us; speedup 1.0000x reference)
//
#include <hip/hip_runtime.h>

#define VOCAB  100000
#define EMB    300
#define BATCH  16384
#define TOTAL  65536
#define NG     5
#define CHUNKS 75                    // EMB/4 float4 chunks per row (1200 B)

#define ABLK     4096                // A: 4 segments per block (4 waves)
#define BTHREADS 3686400             // B threads (each does 2 chunks)
#define BBLK     (BTHREADS / 256)    // 14400
#define NBLK     (ABLK + BBLK)       // 18496

typedef float f4 __attribute__((ext_vector_type(4)));

// ---------------- Single fused kernel ----------------
// A-blocks (bid < ABLK): gather + segment_sum, one wave per segment.
//   Bounds via per-lane serial binary search (lanes 0..4 search the block's
//   5 boundary values; <=5 distinct cache lines per probe step per wave --
//   wave-broadcast-friendly, unlike the R2 64-lines-per-probe lb64 flood).
// B-blocks: plain row gathers, 2 chunks/thread, nt stores.
__global__ __launch_bounds__(256) void fused3_kernel(
    const float* __restrict__ W_in,
    const float* __restrict__ W_out,
    const int*   __restrict__ flat_idx,
    const int*   __restrict__ seg_ids,
    const int*   __restrict__ out_idx,
    const int*   __restrict__ ng_idx,
    float*       __restrict__ in_vec,
    float*       __restrict__ out_vec,
    float*       __restrict__ neg_vec)
{
    const int bid = blockIdx.x;

    if (bid < ABLK) {
        const int wid  = threadIdx.x >> 6;
        const int lane = threadIdx.x & 63;
        const int seg  = bid * 4 + wid;

        // lanes 0..4 binary-search lower_bound(seg_ids, seg_base + lane)
        const int v = bid * 4 + min(lane, 4);
        int lo = 0, hi = TOTAL;
#pragma unroll
        for (int it = 0; it < 16; ++it) {        // 2^16 = TOTAL, converges fully
            const int mid  = (lo + hi) >> 1;
            const bool lt  = seg_ids[mid] < v;
            lo = lt ? mid + 1 : lo;
            hi = lt ? hi      : mid;
        }
        const int start = __shfl(lo, wid);
        const int end   = __shfl(lo, wid + 1);

        f4 acc0 = {0.f, 0.f, 0.f, 0.f};
        f4 acc1 = {0.f, 0.f, 0.f, 0.f};
        const bool extra = lane < (CHUNKS - 64);   // lanes 0..10 own chunk 64+lane

        for (int t0 = start; t0 < end; t0 += 64) {
            const int n = min(64, end - t0);
            // batch-load up to 64 token indices, broadcast via shfl
            const int myidx = (lane < n) ? flat_idx[t0 + lane] : 0;
            for (int j = 0; j < n; ++j) {
                const int idx = __shfl(myidx, j);
                const f4* row = reinterpret_cast<const f4*>(W_in + (size_t)idx * EMB);
                acc0 += row[lane];
                if (extra) acc1 += row[lane + 64];
            }
        }

        f4* dst = reinterpret_cast<f4*>(in_vec + (size_t)seg * EMB);
        __builtin_nontemporal_store(acc0, dst + lane);       // empty segment -> zeros
        if (extra) __builtin_nontemporal_store(acc1, dst + lane + 64);
    } else {
        // ---------- B: plain row gathers, 2 independent chunks per thread ----------
        const int gid = (bid - ABLK) * 256 + (int)threadIdx.x;
#pragma unroll
        for (int k = 0; k < 2; ++k) {
            const int g   = gid + k * BTHREADS;    // < 7,372,800
            const int row = g / CHUNKS;
            const int c   = g - row * CHUNKS;

            int idx;
            float* dstbase;
            if (row < BATCH) {
                idx = out_idx[row];
                dstbase = out_vec + (size_t)row * EMB;
            } else {
                const int rr = row - BATCH;
                idx = ng_idx[rr];
                dstbase = neg_vec + (size_t)rr * EMB;
            }

            const f4* src = reinterpret_cast<const f4*>(W_out + (size_t)idx * EMB);
            const f4 val = src[c];
            __builtin_nontemporal_store(val, reinterpret_cast<f4*>(dstbase) + c);
        }
    }
}

extern "C" void kernel_launch(void* const* d_in, const int* in_sizes, int n_in,
                              void* d_out, int out_size, void* d_ws, size_t ws_size,
                              hipStream_t stream)
{
    const float* W_in   = (const float*)d_in[0];
    const float* W_out  = (const float*)d_in[1];
    const int*   flat   = (const int*)d_in[2];
    const int*   segids = (const int*)d_in[3];
    const int*   outidx = (const int*)d_in[4];
    const int*   ngidx  = (const int*)d_in[5];

    float* o       = (float*)d_out;
    float* in_vec  = o;                                  // [BATCH, EMB]
    float* out_vec = o + (size_t)BATCH * EMB;            // [BATCH, EMB]
    float* neg_vec = o + (size_t)2 * BATCH * EMB;        // [BATCH, NG, EMB]

    fused3_kernel<<<NBLK, 256, 0, stream>>>(W_in, W_out, flat, segids,
                                            outidx, ngidx, in_vec, out_vec, neg_vec);
}

// Round 8
// 60.191 us; speedup vs baseline: 1.0078x; 1.0078x over previous
//
#include <hip/hip_runtime.h>

#define VOCAB  100000
#define EMB    300
#define BATCH  16384
#define TOTAL  65536
#define NG     5
#define CHUNKS 75                    // EMB/4 float4 chunks per row (1200 B)

#define ABLK     4096                // A: 4 segments per block (4 waves)
#define BTHREADS 1843200             // B threads (each does 4 chunks)
#define BBLK     (BTHREADS / 256)    // 7200
#define NBLK     (ABLK + BBLK)       // 11296

typedef float f4 __attribute__((ext_vector_type(4)));

// ---------------- Kernel P: segment boundary table ----------------
// ptr[b] = lower_bound(seg_ids, b) for b in [0, BATCH]; one coalesced sweep.
__global__ __launch_bounds__(256) void bounds_kernel(
    const int* __restrict__ seg_ids,
    int*       __restrict__ ptr)
{
    const int t   = blockIdx.x * 256 + threadIdx.x;      // 0..TOTAL-1
    const int cur = seg_ids[t];
    const int prev = (t == 0) ? -1 : seg_ids[t - 1];
    for (int b = prev + 1; b <= cur; ++b) ptr[b] = t;
    if (t == TOTAL - 1)
        for (int b = cur + 1; b <= BATCH; ++b) ptr[b] = TOTAL;
}

// ---------------- Fused kernel: A-blocks first, then B-blocks ----------------
__global__ __launch_bounds__(256) void fused4_kernel(
    const float* __restrict__ W_in,
    const float* __restrict__ W_out,
    const int*   __restrict__ flat_idx,
    const int*   __restrict__ ptr,
    const int*   __restrict__ out_idx,
    const int*   __restrict__ ng_idx,
    float*       __restrict__ in_vec,
    float*       __restrict__ out_vec,
    float*       __restrict__ neg_vec)
{
    const int bid = blockIdx.x;

    if (bid < ABLK) {
        // ---------- A: gather + segment_sum, one wave per segment ----------
        const int wid  = threadIdx.x >> 6;
        const int lane = threadIdx.x & 63;
        const int seg  = bid * 4 + wid;

        const int start = ptr[seg];
        const int end   = ptr[seg + 1];

        f4 acc0 = {0.f, 0.f, 0.f, 0.f};
        f4 acc1 = {0.f, 0.f, 0.f, 0.f};
        const bool extra = lane < (CHUNKS - 64);   // lanes 0..10 own chunk 64+lane

        for (int t0 = start; t0 < end; t0 += 64) {
            const int n = min(64, end - t0);
            // batch-load up to 64 token indices, broadcast via shfl
            const int myidx = (lane < n) ? flat_idx[t0 + lane] : 0;
            for (int j = 0; j < n; ++j) {
                const int idx = __shfl(myidx, j);
                const f4* row = reinterpret_cast<const f4*>(W_in + (size_t)idx * EMB);
                acc0 += row[lane];
                if (extra) acc1 += row[lane + 64];
            }
        }

        f4* dst = reinterpret_cast<f4*>(in_vec + (size_t)seg * EMB);
        __builtin_nontemporal_store(acc0, dst + lane);       // empty segment -> zeros
        if (extra) __builtin_nontemporal_store(acc1, dst + lane + 64);
    } else {
        // ---------- B: plain row gathers, 4 independent chunks per thread ----------
        const int gid = (bid - ABLK) * 256 + (int)threadIdx.x;
#pragma unroll
        for (int k = 0; k < 4; ++k) {
            const int g   = gid + k * BTHREADS;    // < 7,372,800
            const int row = g / CHUNKS;
            const int c   = g - row * CHUNKS;

            int idx;
            float* dstbase;
            if (row < BATCH) {
                idx = out_idx[row];
                dstbase = out_vec + (size_t)row * EMB;
            } else {
                const int rr = row - BATCH;
                idx = ng_idx[rr];
                dstbase = neg_vec + (size_t)rr * EMB;
            }

            const f4* src = reinterpret_cast<const f4*>(W_out + (size_t)idx * EMB);
            const f4 v = src[c];
            __builtin_nontemporal_store(v, reinterpret_cast<f4*>(dstbase) + c);
        }
    }
}

extern "C" void kernel_launch(void* const* d_in, const int* in_sizes, int n_in,
                              void* d_out, int out_size, void* d_ws, size_t ws_size,
                              hipStream_t stream)
{
    const float* W_in   = (const float*)d_in[0];
    const float* W_out  = (const float*)d_in[1];
    const int*   flat   = (const int*)d_in[2];
    const int*   segids = (const int*)d_in[3];
    const int*   outidx = (const int*)d_in[4];
    const int*   ngidx  = (const int*)d_in[5];

    float* o       = (float*)d_out;
    float* in_vec  = o;                                  // [BATCH, EMB]
    float* out_vec = o + (size_t)BATCH * EMB;            // [BATCH, EMB]
    float* neg_vec = o + (size_t)2 * BATCH * EMB;        // [BATCH, NG, EMB]

    int* ptr = (int*)d_ws;                               // (BATCH+1) ints = 64 KiB + 4

    bounds_kernel<<<TOTAL / 256, 256, 0, stream>>>(segids, ptr);
    fused4_kernel<<<NBLK, 256, 0, stream>>>(W_in, W_out, flat, ptr,
                                            outidx, ngidx, in_vec, out_vec, neg_vec);
}